// Round 2
// baseline (301.054 us; speedup 1.0000x reference)
//
#include <hip/hip_runtime.h>
#include <cstdint>

typedef float floatx4 __attribute__((ext_vector_type(4)));
typedef int intx8 __attribute__((ext_vector_type(8)));

__device__ __forceinline__ unsigned short f2b(float f) {
  union { float f; unsigned u; } v; v.f = f;
  return (unsigned short)((v.u + 0x7FFFu + ((v.u >> 16) & 1u)) >> 16);
}
__device__ __forceinline__ float b2f(unsigned short h) {
  union { unsigned u; float f; } v; v.u = ((unsigned)h) << 16;
  return v.f;
}

__device__ __forceinline__ void gload_lds16(const void* g, void* l) {
  __builtin_amdgcn_global_load_lds(
      (const __attribute__((address_space(1))) void*)g,
      (__attribute__((address_space(3))) void*)l, 16, 0, 0);
}

// ---------------- small prep kernels ----------------

// W (f32) -> fp8 e4m3 of (W * 64); consumed with MX block-scale 2^-6
__global__ void cast_f8x64_kernel(const float* __restrict__ in,
                                  int* __restrict__ out) {
  long i = (long)blockIdx.x * 256 + threadIdx.x;
  float4 v = ((const float4*)in)[i];
  int pk = __builtin_amdgcn_cvt_pk_fp8_f32(v.x * 64.0f, v.y * 64.0f, 0, false);
  pk = __builtin_amdgcn_cvt_pk_fp8_f32(v.z * 64.0f, v.w * 64.0f, pk, true);
  out[i] = pk;
}

// T8[n][m] = fp8(64 * w[n-m]) for m<=n else 0; 2048x2048 bytes, packed int writes
__global__ void build_T8_kernel(const float* __restrict__ w,
                                int* __restrict__ T8) {
  long i = (long)blockIdx.x * 256 + threadIdx.x;  // int index, 512 per row
  int n = (int)(i >> 9);
  int m0 = (int)(i & 511) * 4;
  float v[4];
#pragma unroll
  for (int r = 0; r < 4; ++r) {
    int m = m0 + r;
    v[r] = (m <= n) ? w[n - m] * 64.0f : 0.0f;
  }
  int pk = __builtin_amdgcn_cvt_pk_fp8_f32(v[0], v[1], 0, false);
  pk = __builtin_amdgcn_cvt_pk_fp8_f32(v[2], v[3], pk, true);
  T8[i] = pk;
}

// x (B,2048,1024) f32 -> xT8 (B,1024,2048) fp8 e4m3 (scale 2^0)
__global__ void transpose_cast_f8_kernel(const float* __restrict__ x,
                                         unsigned char* __restrict__ xT) {
  __shared__ float tile[32][33];
  int b = blockIdx.z;
  int n0 = blockIdx.y * 32;
  int d0 = blockIdx.x * 32;
  int tx = threadIdx.x;  // 0..31
  int ty = threadIdx.y;  // 0..7
  for (int i = ty; i < 32; i += 8)
    tile[i][tx] = x[((long)b * 2048 + n0 + i) * 1024 + d0 + tx];
  __syncthreads();
  float a = tile[ty * 4 + 0][tx];
  float c = tile[ty * 4 + 1][tx];
  float e = tile[ty * 4 + 2][tx];
  float f = tile[ty * 4 + 3][tx];
  int pk = __builtin_amdgcn_cvt_pk_fp8_f32(a, c, 0, false);
  pk = __builtin_amdgcn_cvt_pk_fp8_f32(e, f, pk, true);
  *(int*)(xT + ((long)b * 1024 + d0 + tx) * 2048 + n0 + ty * 4) = pk;
}

// ---------------- fp8 GEMM 128x128 (round-0 proven): C = A @ B^T ----------
// Single-buffer sync-drain structure; 33 KB LDS -> 4 blocks/CU TLP hides
// latency cross-block. Used only for GEMM1 (TRI, too few 256-tiles).
// EPI 1: Cf = resid + scale[row]*acc        (conv epilogue)
template <int EPI, int NT, bool TRI>
__global__ __launch_bounds__(256, 4) void gemm_f8(
    const unsigned char* __restrict__ A, const unsigned char* __restrict__ B,
    int Kstride, int Kloop, long zsA, long zsB, long zsC,
    int rx, int ryb, int gxn, unsigned sclA, unsigned sclB,
    const float* __restrict__ resid, const float* __restrict__ scale,
    const float* __restrict__ bias,
    float* __restrict__ Cf, unsigned short* __restrict__ Cb,
    unsigned char* __restrict__ C8) {
  __shared__ __align__(16) unsigned char As[16 * 1040];
  __shared__ __align__(16) unsigned char Bs[16 * 1040];
  const int tid = threadIdx.x;
  const int wid = tid >> 6;
  const int lane = tid & 63;
  const int quad = lane >> 4;
  const int l16 = lane & 15;
  const int wm = (wid >> 1) * 64;
  const int wn = (wid & 1) * 64;

  const int bid = blockIdx.x;
  const int xcd = bid & 7;
  const int ib = bid >> 3;
  const int ci = ib % rx;
  const int ri = ib / rx;
  long bm, bn;
  if (TRI) {
    bm = (long)(ri == 0 ? xcd : 15 - xcd) * 128;
    bn = (long)ci * 128;
  } else {
    const int gx = xcd % gxn;
    const int gy = xcd / gxn;
    bm = (long)(gy * ryb + ri) * 128;
    bn = (long)(gx * rx + ci) * 128;
  }
  const int bz = blockIdx.z;
  const unsigned char* Ab = A + zsA * bz;
  const unsigned char* Bb = B + zsB * bz;

  floatx4 acc[4][4];
#pragma unroll
  for (int i = 0; i < 4; ++i)
#pragma unroll
    for (int j = 0; j < 4; ++j)
      acc[i][j] = floatx4{0.0f, 0.0f, 0.0f, 0.0f};

  const int srow = tid >> 3;          // 0..31 (row within pass)
  const int scol = (tid & 7) * 16;    // byte col
  const unsigned char* gA[4];
  const unsigned char* gB[4];
  unsigned char* lA[4];
  unsigned char* lB[4];
#pragma unroll
  for (int p = 0; p < 4; ++p) {
    gA[p] = Ab + (bm + p * 32 + srow) * (long)Kstride + scol;
    gB[p] = Bb + (bn + p * 32 + srow) * (long)Kstride + scol;
    lA[p] = As + (p * 4 + wid) * 1040;  // wave-uniform base (+lane*16 implicit)
    lB[p] = Bs + (p * 4 + wid) * 1040;
  }

  const int kend = TRI ? min(Kloop, (int)bm + 128) : Kloop;
  for (int kk = 0; kk < kend; kk += 128) {
    __syncthreads();
#pragma unroll
    for (int p = 0; p < 4; ++p) {
      gload_lds16(gA[p] + kk, lA[p]);
      gload_lds16(gB[p] + kk, lB[p]);
    }
    __syncthreads();
    intx8 af[4], bfr[4];
#pragma unroll
    for (int i = 0; i < 4; ++i) {
      const int ra = wm + i * 16 + l16;
      const int off = (ra >> 3) * 1040 + (ra & 7) * 128 + quad * 32;
      union { intx8 v; int4 q[2]; } u;
      u.q[0] = *(const int4*)(As + off);
      u.q[1] = *(const int4*)(As + off + 16);
      af[i] = u.v;
    }
#pragma unroll
    for (int j = 0; j < 4; ++j) {
      const int rb = wn + j * 16 + l16;
      const int off = (rb >> 3) * 1040 + (rb & 7) * 128 + quad * 32;
      union { intx8 v; int4 q[2]; } u;
      u.q[0] = *(const int4*)(Bs + off);
      u.q[1] = *(const int4*)(Bs + off + 16);
      bfr[j] = u.v;
    }
#pragma unroll
    for (int i = 0; i < 4; ++i)
#pragma unroll
      for (int j = 0; j < 4; ++j)
        acc[i][j] = __builtin_amdgcn_mfma_scale_f32_16x16x128_f8f6f4(
            af[i], bfr[j], acc[i][j], 0 /*fp8*/, 0 /*fp8*/,
            0, sclA, 0, sclB);
  }

#pragma unroll
  for (int i = 0; i < 4; ++i)
#pragma unroll
    for (int j = 0; j < 4; ++j)
#pragma unroll
      for (int r = 0; r < 4; ++r) {
        long row = bm + wm + i * 16 + quad * 4 + r;
        long col = bn + wn + j * 16 + l16;
        long idx = (long)bz * zsC + row * (long)NT + col;
        float v = acc[i][j][r];
        if (EPI == 0) {
          Cb[idx] = f2b(v);
        } else if (EPI == 1) {
          Cf[idx] = resid[idx] + scale[row] * v;
        } else {
          v += bias[col];
          float u = v * (0.7978845608f + 0.0356774081f * v * v);
          float u2 = u * u;
          float t = __fdividef(u * (15.0f + u2), 15.0f + 6.0f * u2);
          t = fminf(fmaxf(t, -1.0f), 1.0f);
          float g = 0.5f * v * (1.0f + t);
          int pk = __builtin_amdgcn_cvt_pk_fp8_f32(g, 0.0f, 0, false);
          C8[idx] = (unsigned char)(pk & 0xFF);
        }
      }
}

// ---------------- fp8 GEMM 256x256 (8 waves): C = A @ B^T ------------------
// BM=BN=256, BK=128, 512 thr, wave tile 128x64 (2M x 4N wave grid).
// Per K-step: 256 MFMAs (~2200 CU-cyc) vs 64 KB staging (~1200 cyc L2) ->
// compute phase covers load latency; double-buffered LDS (133 KB, 1 blk/CU)
// with counted s_waitcnt vmcnt(8) so next-tile loads stay in flight across
// the barrier (T3+T4). setprio(1) around MFMA cluster (T5, role-split waves).
// EPI 0: Cb = bf16(acc)                     (split-K partial, GEMM3)
// EPI 2: C8 = fp8(gelu_pade(acc+bias))      (MLP up, GEMM2)
template <int EPI, int NT>
__global__ __launch_bounds__(512, 2) void gemm_f8_256(
    const unsigned char* __restrict__ A, const unsigned char* __restrict__ B,
    int Kstride, int Kloop, long zsA, long zsB, long zsC,
    int rx, int ryb, int gxn, unsigned sclA, unsigned sclB,
    const float* __restrict__ bias,
    unsigned short* __restrict__ Cb, unsigned char* __restrict__ C8) {
  // per operand: 2 buffers x 32 chunks x 1040 B = 66560 B
  __shared__ __align__(16) unsigned char As[2 * 32 * 1040];
  __shared__ __align__(16) unsigned char Bs[2 * 32 * 1040];
  const int tid = threadIdx.x;
  const int wid = tid >> 6;        // 0..7
  const int lane = tid & 63;
  const int quad = lane >> 4;
  const int l16 = lane & 15;
  const int wm = (wid >> 2) * 128; // 2 waves along M
  const int wn = (wid & 3) * 64;   // 4 waves along N

  const int bid = blockIdx.x;
  const int xcd = bid & 7;
  const int ib = bid >> 3;
  const int ci = ib % rx;
  const int ri = ib / rx;
  const int gx = xcd % gxn;
  const int gy = xcd / gxn;
  const long bm = (long)(gy * ryb + ri) * 256;
  const long bn = (long)(gx * rx + ci) * 256;
  const int bz = blockIdx.z;
  const unsigned char* Ab = A + zsA * bz;
  const unsigned char* Bb = B + zsB * bz;

  floatx4 acc[8][4];
#pragma unroll
  for (int i = 0; i < 8; ++i)
#pragma unroll
    for (int j = 0; j < 4; ++j)
      acc[i][j] = floatx4{0.0f, 0.0f, 0.0f, 0.0f};

  // staging: 8 passes x 512 thr x 16B = 64 KB; pass p of A: wave w stages
  // chunk p*8+w (rows 8*(p*8+w) .. +8), lane l -> row +(l>>3), col (l&7)*16
  const int srow = wid * 8 + (lane >> 3);  // row within 64-row pass group
  const int scol = (lane & 7) * 16;
  const unsigned char* gA[4];
  const unsigned char* gB[4];
  unsigned char* lA[4];
  unsigned char* lB[4];
#pragma unroll
  for (int p = 0; p < 4; ++p) {
    gA[p] = Ab + (bm + p * 64 + srow) * (long)Kstride + scol;
    gB[p] = Bb + (bn + p * 64 + srow) * (long)Kstride + scol;
    lA[p] = As + (p * 8 + wid) * 1040;  // wave-uniform base (+lane*16 implicit)
    lB[p] = Bs + (p * 8 + wid) * 1040;
  }

  // loop-invariant fragment byte offsets within a buffer
  int offA[8], offB[4];
#pragma unroll
  for (int i = 0; i < 8; ++i) {
    const int ra = wm + i * 16 + l16;
    offA[i] = (ra >> 3) * 1040 + (ra & 7) * 128 + quad * 32;
  }
#pragma unroll
  for (int j = 0; j < 4; ++j) {
    const int rb = wn + j * 16 + l16;
    offB[j] = (rb >> 3) * 1040 + (rb & 7) * 128 + quad * 32;
  }

  // prologue: stage tile 0 into buffer 0
#pragma unroll
  for (int p = 0; p < 4; ++p) {
    gload_lds16(gA[p], lA[p]);
    gload_lds16(gB[p], lB[p]);
  }

  int so = 0;  // current buffer byte offset (0 or 33280)
  for (int kk = 0; kk < Kloop; kk += 128) {
    const int kn = kk + 128;
    if (kn < Kloop) {
      const int po = so ^ 33280;
#pragma unroll
      for (int p = 0; p < 4; ++p) {
        gload_lds16(gA[p] + kn, lA[p] + po);
        gload_lds16(gB[p] + kn, lB[p] + po);
      }
      // wait for CURRENT tile (issued last iter); 8 newest stay in flight
      asm volatile("s_waitcnt vmcnt(8)" ::: "memory");
    } else {
      asm volatile("s_waitcnt vmcnt(0)" ::: "memory");
    }
    __builtin_amdgcn_s_barrier();

    intx8 bfr[4];
#pragma unroll
    for (int j = 0; j < 4; ++j) {
      union { intx8 v; int4 q[2]; } u;
      u.q[0] = *(const int4*)(Bs + so + offB[j]);
      u.q[1] = *(const int4*)(Bs + so + offB[j] + 16);
      bfr[j] = u.v;
    }
    __builtin_amdgcn_s_setprio(1);
#pragma unroll
    for (int i = 0; i < 8; ++i) {
      union { intx8 v; int4 q[2]; } u;
      u.q[0] = *(const int4*)(As + so + offA[i]);
      u.q[1] = *(const int4*)(As + so + offA[i] + 16);
      intx8 af = u.v;
#pragma unroll
      for (int j = 0; j < 4; ++j)
        acc[i][j] = __builtin_amdgcn_mfma_scale_f32_16x16x128_f8f6f4(
            af, bfr[j], acc[i][j], 0 /*fp8*/, 0 /*fp8*/,
            0, sclA, 0, sclB);
    }
    __builtin_amdgcn_s_setprio(0);
    __builtin_amdgcn_s_barrier();  // reads done before next-iter overwrite
    so ^= 33280;
  }

#pragma unroll
  for (int i = 0; i < 8; ++i)
#pragma unroll
    for (int j = 0; j < 4; ++j)
#pragma unroll
      for (int r = 0; r < 4; ++r) {
        long row = bm + wm + i * 16 + quad * 4 + r;
        long col = bn + wn + j * 16 + l16;
        long idx = (long)bz * zsC + row * (long)NT + col;
        float v = acc[i][j][r];
        if (EPI == 0) {
          Cb[idx] = f2b(v);
        } else {
          v += bias[col];
          float u = v * (0.7978845608f + 0.0356774081f * v * v);
          float u2 = u * u;
          float t = __fdividef(u * (15.0f + u2), 15.0f + 6.0f * u2);
          t = fminf(fmaxf(t, -1.0f), 1.0f);
          float g = 0.5f * v * (1.0f + t);
          int pk = __builtin_amdgcn_cvt_pk_fp8_f32(g, 0.0f, 0, false);
          C8[idx] = (unsigned char)(pk & 0xFF);
        }
      }
}

// ---------------- LayerNorm over D=1024, one block per row ----------------
__global__ __launch_bounds__(256) void ln_kernel(
    const float* __restrict__ in, const float* __restrict__ w,
    const float* __restrict__ b, unsigned short* __restrict__ outb,
    int* __restrict__ outf8) {
  const long row = blockIdx.x;
  const int tid = threadIdx.x;
  float4 v = ((const float4*)in)[row * 256 + tid];
  float s = v.x + v.y + v.z + v.w;
  float ss = v.x * v.x + v.y * v.y + v.z * v.z + v.w * v.w;
#pragma unroll
  for (int off = 32; off > 0; off >>= 1) {
    s += __shfl_down(s, off);
    ss += __shfl_down(ss, off);
  }
  __shared__ float red[8];
  const int wid = tid >> 6, lane = tid & 63;
  if (lane == 0) { red[wid] = s; red[4 + wid] = ss; }
  __syncthreads();
  s = red[0] + red[1] + red[2] + red[3];
  ss = red[4] + red[5] + red[6] + red[7];
  const float mu = s * (1.0f / 1024.0f);
  const float var = ss * (1.0f / 1024.0f) - mu * mu;
  const float rs = rsqrtf(var + 1e-5f);
  float4 wv = ((const float4*)w)[tid];
  float4 bv = ((const float4*)b)[tid];
  float o0 = (v.x - mu) * rs * wv.x + bv.x;
  float o1 = (v.y - mu) * rs * wv.y + bv.y;
  float o2 = (v.z - mu) * rs * wv.z + bv.z;
  float o3 = (v.w - mu) * rs * wv.w + bv.w;
  ushort4 u{f2b(o0), f2b(o1), f2b(o2), f2b(o3)};
  ((ushort4*)outb)[row * 256 + tid] = u;
  int pk = __builtin_amdgcn_cvt_pk_fp8_f32(o0, o1, 0, false);
  pk = __builtin_amdgcn_cvt_pk_fp8_f32(o2, o3, pk, true);
  outf8[row * 256 + tid] = pk;
}

// LN2 fused: v = x1 + scalar*(y0+y1+b2); out = LN(v)*w + b
__global__ __launch_bounds__(256) void ln2_fused_kernel(
    const unsigned short* __restrict__ y0, const unsigned short* __restrict__ y1,
    const unsigned short* __restrict__ x1b, const float* __restrict__ b2,
    const float* __restrict__ scalar_p, const float* __restrict__ w,
    const float* __restrict__ b, float* __restrict__ out) {
  const long row = blockIdx.x;
  const int tid = threadIdx.x;
  ushort4 a4 = ((const ushort4*)y0)[row * 256 + tid];
  ushort4 c4 = ((const ushort4*)y1)[row * 256 + tid];
  ushort4 xr = ((const ushort4*)x1b)[row * 256 + tid];
  float4 bias = ((const float4*)b2)[tid];
  const float scl = scalar_p[0];
  float4 v;
  v.x = b2f(xr.x) + scl * (b2f(a4.x) + b2f(c4.x) + bias.x);
  v.y = b2f(xr.y) + scl * (b2f(a4.y) + b2f(c4.y) + bias.y);
  v.z = b2f(xr.z) + scl * (b2f(a4.z) + b2f(c4.z) + bias.z);
  v.w = b2f(xr.w) + scl * (b2f(a4.w) + b2f(c4.w) + bias.w);
  float s = v.x + v.y + v.z + v.w;
  float ss = v.x * v.x + v.y * v.y + v.z * v.z + v.w * v.w;
#pragma unroll
  for (int off = 32; off > 0; off >>= 1) {
    s += __shfl_down(s, off);
    ss += __shfl_down(ss, off);
  }
  __shared__ float red[8];
  const int wid = tid >> 6, lane = tid & 63;
  if (lane == 0) { red[wid] = s; red[4 + wid] = ss; }
  __syncthreads();
  s = red[0] + red[1] + red[2] + red[3];
  ss = red[4] + red[5] + red[6] + red[7];
  const float mu = s * (1.0f / 1024.0f);
  const float var = ss * (1.0f / 1024.0f) - mu * mu;
  const float rs = rsqrtf(var + 1e-5f);
  float4 wv = ((const float4*)w)[tid];
  float4 bv = ((const float4*)b)[tid];
  float4 o;
  o.x = (v.x - mu) * rs * wv.x + bv.x;
  o.y = (v.y - mu) * rs * wv.y + bv.y;
  o.z = (v.z - mu) * rs * wv.z + bv.z;
  o.w = (v.w - mu) * rs * wv.w + bv.w;
  ((float4*)out)[row * 256 + tid] = o;
}

// ---------------- launch ----------------
extern "C" void kernel_launch(void* const* d_in, const int* in_sizes, int n_in,
                              void* d_out, int out_size, void* d_ws, size_t ws_size,
                              hipStream_t stream) {
  const float* x      = (const float*)d_in[0];
  const float* wconv  = (const float*)d_in[1];
  const float* scale  = (const float*)d_in[2];
  const float* ln1w   = (const float*)d_in[3];
  const float* ln1b   = (const float*)d_in[4];
  const float* W1     = (const float*)d_in[5];
  const float* b1     = (const float*)d_in[6];
  const float* W2     = (const float*)d_in[7];
  const float* b2     = (const float*)d_in[8];
  const float* scalar = (const float*)d_in[9];
  const float* ln2w   = (const float*)d_in[10];
  const float* ln2b   = (const float*)d_in[11];
  float* out = (float*)d_out;

  const unsigned SCL_1  = 0x7F7F7F7Fu;  // 2^0 per-block scales
  const unsigned SCL_64 = 0x79797979u;  // 2^-6 (operand pre-scaled x64)

  char* ws = (char*)d_ws;
  unsigned char* xT8   = (unsigned char*)ws;  ws += (size_t)4 * 1024 * 2048;     //  8 MB
  unsigned char* T8    = (unsigned char*)ws;  ws += (size_t)2048 * 2048;         //  4 MB
  unsigned char* W1f8  = (unsigned char*)ws;  ws += (size_t)4096 * 1024;         //  4 MB
  unsigned char* W2f8  = (unsigned char*)ws;  ws += (size_t)4096 * 1024;         //  4 MB
  float* y             = (float*)ws;          ws += (size_t)8192 * 1024 * 4;     // 32 MB
  unsigned short* yb   = (unsigned short*)ws; ws += (size_t)2 * 8192 * 1024 * 2; // 32 MB (split-K bf16 partials)
  unsigned short* x1b  = (unsigned short*)ws; ws += (size_t)8192 * 1024 * 2;     // 16 MB
  unsigned char* x1f8  = (unsigned char*)ws;  ws += (size_t)8192 * 1024;         //  8 MB
  unsigned char* h8    = (unsigned char*)ws;  ws += (size_t)8192 * 4096;         // 32 MB

  // prep
  cast_f8x64_kernel<<<4096, 256, 0, stream>>>(W1, (int*)W1f8);
  cast_f8x64_kernel<<<4096, 256, 0, stream>>>(W2, (int*)W2f8);
  build_T8_kernel<<<4096, 256, 0, stream>>>(wconv, (int*)T8);
  transpose_cast_f8_kernel<<<dim3(32, 64, 4), dim3(32, 8), 0, stream>>>(x, xT8);

  // GEMM1 (fp8, TRI, 128-tile): per batch, conv = T @ xT_b^T ; y = x + scale*conv
  gemm_f8<1, 1024, true><<<dim3(128, 1, 4), 256, 0, stream>>>(
      T8, xT8, 2048, 2048, 0L, (long)1024 * 2048, (long)2048 * 1024,
      8, 0, 0, SCL_64, SCL_1, x, scale, nullptr, y, nullptr, nullptr);
  // LN1 -> x1 (bf16 residual + fp8 GEMM operand)
  ln_kernel<<<8192, 256, 0, stream>>>(y, ln1w, ln1b, x1b, (int*)x1f8);
  // GEMM2 (fp8, 256-tile): h = gelu(x1 @ W1^T + b1) -> fp8
  // grid 32x16 tiles = 512 blocks; XCD regions 8x8 (gxn=2)
  gemm_f8_256<2, 4096><<<dim3(512, 1, 1), 512, 0, stream>>>(
      x1f8, W1f8, 1024, 1024, 0L, 0L, 0L,
      8, 8, 2, SCL_1, SCL_64, b1, nullptr, h8);
  // GEMM3 (fp8, 256-tile) split-K=2: yb = bf16 partial h @ W2^T
  // grid 32x4 tiles = 128 blocks x z2; XCD regions 4x4 stacked in M (gxn=1)
  gemm_f8_256<0, 1024><<<dim3(128, 1, 2), 512, 0, stream>>>(
      h8, W2f8, 4096, 2048, 2048L, 2048L, (long)8192 * 1024,
      4, 4, 1, SCL_1, SCL_64, nullptr, yb, nullptr);
  // LN2 fused: out = LN(x1 + scalar*(yb0+yb1+b2))
  ln2_fused_kernel<<<8192, 256, 0, stream>>>(
      yb, yb + (size_t)8192 * 1024, x1b, b2, scalar, ln2w, ln2b, out);
}

// Round 3
// 299.469 us; speedup vs baseline: 1.0053x; 1.0053x over previous
//
#include <hip/hip_runtime.h>
#include <cstdint>

typedef float floatx4 __attribute__((ext_vector_type(4)));
typedef int intx8 __attribute__((ext_vector_type(8)));

__device__ __forceinline__ unsigned short f2b(float f) {
  union { float f; unsigned u; } v; v.f = f;
  return (unsigned short)((v.u + 0x7FFFu + ((v.u >> 16) & 1u)) >> 16);
}
__device__ __forceinline__ float b2f(unsigned short h) {
  union { unsigned u; float f; } v; v.u = ((unsigned)h) << 16;
  return v.f;
}

__device__ __forceinline__ void gload_lds16(const void* g, void* l) {
  __builtin_amdgcn_global_load_lds(
      (const __attribute__((address_space(1))) void*)g,
      (__attribute__((address_space(3))) void*)l, 16, 0, 0);
}

__device__ __forceinline__ intx8 lds_read32(const unsigned char* p) {
  union { intx8 v; int4 q[2]; } u;
  u.q[0] = *(const int4*)p;
  u.q[1] = *(const int4*)(p + 16);
  return u.v;
}

// Swizzled staging byte-column: LDS chunk (row, q) receives global chunk
// q ^ (row&3).  row-in-chunk = lane>>3, q = (lane>>1)&3, s = lane&1.
__device__ __forceinline__ int swz_scol(int lane) {
  const int q = (lane >> 1) & 3;
  const int r3 = (lane >> 3) & 3;
  const int sbit = lane & 1;
  return ((((q ^ r3) << 1) | sbit) << 4);
}

// ---------------- small prep kernels ----------------

__global__ void cast_f8x64_kernel(const float* __restrict__ in,
                                  int* __restrict__ out) {
  long i = (long)blockIdx.x * 256 + threadIdx.x;
  float4 v = ((const float4*)in)[i];
  int pk = __builtin_amdgcn_cvt_pk_fp8_f32(v.x * 64.0f, v.y * 64.0f, 0, false);
  pk = __builtin_amdgcn_cvt_pk_fp8_f32(v.z * 64.0f, v.w * 64.0f, pk, true);
  out[i] = pk;
}

__global__ void build_T8_kernel(const float* __restrict__ w,
                                int* __restrict__ T8) {
  long i = (long)blockIdx.x * 256 + threadIdx.x;
  int n = (int)(i >> 9);
  int m0 = (int)(i & 511) * 4;
  float v[4];
#pragma unroll
  for (int r = 0; r < 4; ++r) {
    int m = m0 + r;
    v[r] = (m <= n) ? w[n - m] * 64.0f : 0.0f;
  }
  int pk = __builtin_amdgcn_cvt_pk_fp8_f32(v[0], v[1], 0, false);
  pk = __builtin_amdgcn_cvt_pk_fp8_f32(v[2], v[3], pk, true);
  T8[i] = pk;
}

__global__ void transpose_cast_f8_kernel(const float* __restrict__ x,
                                         unsigned char* __restrict__ xT) {
  __shared__ float tile[32][33];
  int b = blockIdx.z;
  int n0 = blockIdx.y * 32;
  int d0 = blockIdx.x * 32;
  int tx = threadIdx.x;
  int ty = threadIdx.y;
  for (int i = ty; i < 32; i += 8)
    tile[i][tx] = x[((long)b * 2048 + n0 + i) * 1024 + d0 + tx];
  __syncthreads();
  float a = tile[ty * 4 + 0][tx];
  float c = tile[ty * 4 + 1][tx];
  float e = tile[ty * 4 + 2][tx];
  float f = tile[ty * 4 + 3][tx];
  int pk = __builtin_amdgcn_cvt_pk_fp8_f32(a, c, 0, false);
  pk = __builtin_amdgcn_cvt_pk_fp8_f32(e, f, pk, true);
  *(int*)(xT + ((long)b * 1024 + d0 + tx) * 2048 + n0 + ty * 4) = pk;
}

// ---------------- fp8 GEMM 128x128 (GEMM1 only): C = A @ B^T ---------------
// r0-proven 2-phase sync-drain, 4 blocks/CU; + bank-conflict XOR swizzle.
template <int EPI, int NT, bool TRI>
__global__ __launch_bounds__(256, 4) void gemm_f8(
    const unsigned char* __restrict__ A, const unsigned char* __restrict__ B,
    int Kstride, int Kloop, long zsA, long zsB, long zsC,
    int rx, int ryb, int gxn, unsigned sclA, unsigned sclB,
    const float* __restrict__ resid, const float* __restrict__ scale,
    const float* __restrict__ bias,
    float* __restrict__ Cf, unsigned short* __restrict__ Cb,
    unsigned char* __restrict__ C8) {
  __shared__ __align__(16) unsigned char As[16 * 1040];
  __shared__ __align__(16) unsigned char Bs[16 * 1040];
  const int tid = threadIdx.x;
  const int wid = tid >> 6;
  const int lane = tid & 63;
  const int quad = lane >> 4;
  const int l16 = lane & 15;
  const int wm = (wid >> 1) * 64;
  const int wn = (wid & 1) * 64;

  const int bid = blockIdx.x;
  const int xcd = bid & 7;
  const int ib = bid >> 3;
  const int ci = ib % rx;
  const int ri = ib / rx;
  long bm, bn;
  if (TRI) {
    bm = (long)(ri == 0 ? xcd : 15 - xcd) * 128;
    bn = (long)ci * 128;
  } else {
    const int gx = xcd % gxn;
    const int gy = xcd / gxn;
    bm = (long)(gy * ryb + ri) * 128;
    bn = (long)(gx * rx + ci) * 128;
  }
  const int bz = blockIdx.z;
  const unsigned char* Ab = A + zsA * bz;
  const unsigned char* Bb = B + zsB * bz;

  floatx4 acc[4][4];
#pragma unroll
  for (int i = 0; i < 4; ++i)
#pragma unroll
    for (int j = 0; j < 4; ++j)
      acc[i][j] = floatx4{0.0f, 0.0f, 0.0f, 0.0f};

  const int srow = tid >> 3;
  const int scol = swz_scol(lane);   // pre-swizzled source column
  const unsigned char* gA[4];
  const unsigned char* gB[4];
  unsigned char* lA[4];
  unsigned char* lB[4];
#pragma unroll
  for (int p = 0; p < 4; ++p) {
    gA[p] = Ab + (bm + p * 32 + srow) * (long)Kstride + scol;
    gB[p] = Bb + (bn + p * 32 + srow) * (long)Kstride + scol;
    lA[p] = As + (p * 4 + wid) * 1040;
    lB[p] = Bs + (p * 4 + wid) * 1040;
  }

  const int kend = TRI ? min(Kloop, (int)bm + 128) : Kloop;
  for (int kk = 0; kk < kend; kk += 128) {
    __syncthreads();
#pragma unroll
    for (int p = 0; p < 4; ++p) {
      gload_lds16(gA[p] + kk, lA[p]);
      gload_lds16(gB[p] + kk, lB[p]);
    }
    __syncthreads();
    intx8 af[4], bfr[4];
#pragma unroll
    for (int i = 0; i < 4; ++i) {
      const int ra = wm + i * 16 + l16;
      const int off = (ra >> 3) * 1040 + (ra & 7) * 128 + ((quad ^ (ra & 3)) << 5);
      af[i] = lds_read32(As + off);
    }
#pragma unroll
    for (int j = 0; j < 4; ++j) {
      const int rb = wn + j * 16 + l16;
      const int off = (rb >> 3) * 1040 + (rb & 7) * 128 + ((quad ^ (rb & 3)) << 5);
      bfr[j] = lds_read32(Bs + off);
    }
#pragma unroll
    for (int i = 0; i < 4; ++i)
#pragma unroll
      for (int j = 0; j < 4; ++j)
        acc[i][j] = __builtin_amdgcn_mfma_scale_f32_16x16x128_f8f6f4(
            af[i], bfr[j], acc[i][j], 0, 0, 0, sclA, 0, sclB);
  }

#pragma unroll
  for (int i = 0; i < 4; ++i)
#pragma unroll
    for (int j = 0; j < 4; ++j)
#pragma unroll
      for (int r = 0; r < 4; ++r) {
        long row = bm + wm + i * 16 + quad * 4 + r;
        long col = bn + wn + j * 16 + l16;
        long idx = (long)bz * zsC + row * (long)NT + col;
        float v = acc[i][j][r];
        if (EPI == 0) {
          Cb[idx] = f2b(v);
        } else if (EPI == 1) {
          Cf[idx] = resid[idx] + scale[row] * v;
        } else {
          v += bias[col];
          float u = v * (0.7978845608f + 0.0356774081f * v * v);
          float u2 = u * u;
          float t = __fdividef(u * (15.0f + u2), 15.0f + 6.0f * u2);
          t = fminf(fmaxf(t, -1.0f), 1.0f);
          float g = 0.5f * v * (1.0f + t);
          int pk = __builtin_amdgcn_cvt_pk_fp8_f32(g, 0.0f, 0, false);
          C8[idx] = (unsigned char)(pk & 0xFF);
        }
      }
}

// ---------------- fp8 GEMM 256x256, 4-phase pipelined (GEMM2/3) ------------
// 8 waves (2M x 4N), wave tile 128x64, BK=128, double-buffered LDS (133 KB).
// Per K-tile, 4 phases: {ds_read A i-pair (+all B in ph0) -> issue next-tile
// gload_lds (all 8 by ph1) -> s_barrier -> lgkmcnt(0) -> setprio'd 8 MFMA ->
// s_barrier}.  Single vmcnt(0) before ph3's trailing barrier (>=2-phase
// cover).  XOR bank swizzle on stage-source + frag reads.
template <int EPI, int NT>
__global__ __launch_bounds__(512, 2) void gemm_f8_256(
    const unsigned char* __restrict__ A, const unsigned char* __restrict__ B,
    int Kstride, int Kloop, long zsA, long zsB, long zsC,
    int rx, int ryb, int gxn, unsigned sclA, unsigned sclB,
    const float* __restrict__ bias,
    unsigned short* __restrict__ Cb, unsigned char* __restrict__ C8) {
  __shared__ __align__(16) unsigned char As[2 * 32 * 1040];
  __shared__ __align__(16) unsigned char Bs[2 * 32 * 1040];
  const int tid = threadIdx.x;
  const int wid = tid >> 6;
  const int lane = tid & 63;
  const int quad = lane >> 4;
  const int l16 = lane & 15;
  const int wm = (wid >> 2) * 128;
  const int wn = (wid & 3) * 64;

  const int bid = blockIdx.x;
  const int xcd = bid & 7;
  const int ib = bid >> 3;
  const int ci = ib % rx;
  const int ri = ib / rx;
  const int gx = xcd % gxn;
  const int gy = xcd / gxn;
  const long bm = (long)(gy * ryb + ri) * 256;
  const long bn = (long)(gx * rx + ci) * 256;
  const int bz = blockIdx.z;
  const unsigned char* Ab = A + zsA * bz;
  const unsigned char* Bb = B + zsB * bz;

  floatx4 acc[8][4];
#pragma unroll
  for (int i = 0; i < 8; ++i)
#pragma unroll
    for (int j = 0; j < 4; ++j)
      acc[i][j] = floatx4{0.0f, 0.0f, 0.0f, 0.0f};

  const int srow = wid * 8 + (lane >> 3);
  const int scol = swz_scol(lane);
  const unsigned char* gA[4];
  const unsigned char* gB[4];
  unsigned char* lA[4];
  unsigned char* lB[4];
#pragma unroll
  for (int p = 0; p < 4; ++p) {
    gA[p] = Ab + (bm + p * 64 + srow) * (long)Kstride + scol;
    gB[p] = Bb + (bn + p * 64 + srow) * (long)Kstride + scol;
    lA[p] = As + (p * 8 + wid) * 1040;
    lB[p] = Bs + (p * 8 + wid) * 1040;
  }

  int offA[8], offB[4];
#pragma unroll
  for (int i = 0; i < 8; ++i) {
    const int ra = wm + i * 16 + l16;
    offA[i] = (ra >> 3) * 1040 + (ra & 7) * 128 + ((quad ^ (ra & 3)) << 5);
  }
#pragma unroll
  for (int j = 0; j < 4; ++j) {
    const int rb = wn + j * 16 + l16;
    offB[j] = (rb >> 3) * 1040 + (rb & 7) * 128 + ((quad ^ (rb & 3)) << 5);
  }

  // prologue: tile 0 -> buffer 0, full drain, barrier
#pragma unroll
  for (int p = 0; p < 4; ++p) {
    gload_lds16(gA[p], lA[p]);
    gload_lds16(gB[p], lB[p]);
  }
  asm volatile("s_waitcnt vmcnt(0)" ::: "memory");
  __builtin_amdgcn_s_barrier();

#define LGKM0() do { asm volatile("s_waitcnt lgkmcnt(0)" ::: "memory"); \
                     __builtin_amdgcn_sched_barrier(0); } while (0)

  int so = 0;
  for (int kk = 0; kk < Kloop; kk += 128) {
    const int kn = kk + 128;
    const bool nxt = kn < Kloop;
    const int po = so ^ 33280;
    intx8 bfr[4], af0, af1;

    // ---- phase 0: B frags + A0,A1; issue 4 next-tile loads ----
#pragma unroll
    for (int j = 0; j < 4; ++j) bfr[j] = lds_read32(Bs + so + offB[j]);
    af0 = lds_read32(As + so + offA[0]);
    af1 = lds_read32(As + so + offA[1]);
    if (nxt) {
      gload_lds16(gA[0] + kn, lA[0] + po);
      gload_lds16(gA[1] + kn, lA[1] + po);
      gload_lds16(gB[0] + kn, lB[0] + po);
      gload_lds16(gB[1] + kn, lB[1] + po);
    }
    __builtin_amdgcn_s_barrier();
    LGKM0();
    __builtin_amdgcn_s_setprio(1);
#pragma unroll
    for (int j = 0; j < 4; ++j) {
      acc[0][j] = __builtin_amdgcn_mfma_scale_f32_16x16x128_f8f6f4(
          af0, bfr[j], acc[0][j], 0, 0, 0, sclA, 0, sclB);
      acc[1][j] = __builtin_amdgcn_mfma_scale_f32_16x16x128_f8f6f4(
          af1, bfr[j], acc[1][j], 0, 0, 0, sclA, 0, sclB);
    }
    __builtin_amdgcn_s_setprio(0);
    __builtin_amdgcn_s_barrier();

    // ---- phase 1: A2,A3; issue remaining 4 next-tile loads ----
    af0 = lds_read32(As + so + offA[2]);
    af1 = lds_read32(As + so + offA[3]);
    if (nxt) {
      gload_lds16(gA[2] + kn, lA[2] + po);
      gload_lds16(gA[3] + kn, lA[3] + po);
      gload_lds16(gB[2] + kn, lB[2] + po);
      gload_lds16(gB[3] + kn, lB[3] + po);
    }
    __builtin_amdgcn_s_barrier();
    LGKM0();
    __builtin_amdgcn_s_setprio(1);
#pragma unroll
    for (int j = 0; j < 4; ++j) {
      acc[2][j] = __builtin_amdgcn_mfma_scale_f32_16x16x128_f8f6f4(
          af0, bfr[j], acc[2][j], 0, 0, 0, sclA, 0, sclB);
      acc[3][j] = __builtin_amdgcn_mfma_scale_f32_16x16x128_f8f6f4(
          af1, bfr[j], acc[3][j], 0, 0, 0, sclA, 0, sclB);
    }
    __builtin_amdgcn_s_setprio(0);
    __builtin_amdgcn_s_barrier();

    // ---- phase 2: A4,A5 ----
    af0 = lds_read32(As + so + offA[4]);
    af1 = lds_read32(As + so + offA[5]);
    __builtin_amdgcn_s_barrier();
    LGKM0();
    __builtin_amdgcn_s_setprio(1);
#pragma unroll
    for (int j = 0; j < 4; ++j) {
      acc[4][j] = __builtin_amdgcn_mfma_scale_f32_16x16x128_f8f6f4(
          af0, bfr[j], acc[4][j], 0, 0, 0, sclA, 0, sclB);
      acc[5][j] = __builtin_amdgcn_mfma_scale_f32_16x16x128_f8f6f4(
          af1, bfr[j], acc[5][j], 0, 0, 0, sclA, 0, sclB);
    }
    __builtin_amdgcn_s_setprio(0);
    __builtin_amdgcn_s_barrier();

    // ---- phase 3: A6,A7; tile-boundary vmcnt before trailing barrier ----
    af0 = lds_read32(As + so + offA[6]);
    af1 = lds_read32(As + so + offA[7]);
    __builtin_amdgcn_s_barrier();
    LGKM0();
    __builtin_amdgcn_s_setprio(1);
#pragma unroll
    for (int j = 0; j < 4; ++j) {
      acc[6][j] = __builtin_amdgcn_mfma_scale_f32_16x16x128_f8f6f4(
          af0, bfr[j], acc[6][j], 0, 0, 0, sclA, 0, sclB);
      acc[7][j] = __builtin_amdgcn_mfma_scale_f32_16x16x128_f8f6f4(
          af1, bfr[j], acc[7][j], 0, 0, 0, sclA, 0, sclB);
    }
    __builtin_amdgcn_s_setprio(0);
    if (nxt) asm volatile("s_waitcnt vmcnt(0)" ::: "memory");
    __builtin_amdgcn_s_barrier();
    so = po;
  }
#undef LGKM0

#pragma unroll
  for (int i = 0; i < 8; ++i)
#pragma unroll
    for (int j = 0; j < 4; ++j)
#pragma unroll
      for (int r = 0; r < 4; ++r) {
        long row = bm + wm + i * 16 + quad * 4 + r;
        long col = bn + wn + j * 16 + l16;
        long idx = (long)bz * zsC + row * (long)NT + col;
        float v = acc[i][j][r];
        if (EPI == 0) {
          Cb[idx] = f2b(v);
        } else {
          v += bias[col];
          float u = v * (0.7978845608f + 0.0356774081f * v * v);
          float u2 = u * u;
          float t = __fdividef(u * (15.0f + u2), 15.0f + 6.0f * u2);
          t = fminf(fmaxf(t, -1.0f), 1.0f);
          float g = 0.5f * v * (1.0f + t);
          int pk = __builtin_amdgcn_cvt_pk_fp8_f32(g, 0.0f, 0, false);
          C8[idx] = (unsigned char)(pk & 0xFF);
        }
      }
}

// ---------------- LayerNorm over D=1024, one block per row ----------------
__global__ __launch_bounds__(256) void ln_kernel(
    const float* __restrict__ in, const float* __restrict__ w,
    const float* __restrict__ b, unsigned short* __restrict__ outb,
    int* __restrict__ outf8) {
  const long row = blockIdx.x;
  const int tid = threadIdx.x;
  float4 v = ((const float4*)in)[row * 256 + tid];
  float s = v.x + v.y + v.z + v.w;
  float ss = v.x * v.x + v.y * v.y + v.z * v.z + v.w * v.w;
#pragma unroll
  for (int off = 32; off > 0; off >>= 1) {
    s += __shfl_down(s, off);
    ss += __shfl_down(ss, off);
  }
  __shared__ float red[8];
  const int wid = tid >> 6, lane = tid & 63;
  if (lane == 0) { red[wid] = s; red[4 + wid] = ss; }
  __syncthreads();
  s = red[0] + red[1] + red[2] + red[3];
  ss = red[4] + red[5] + red[6] + red[7];
  const float mu = s * (1.0f / 1024.0f);
  const float var = ss * (1.0f / 1024.0f) - mu * mu;
  const float rs = rsqrtf(var + 1e-5f);
  float4 wv = ((const float4*)w)[tid];
  float4 bv = ((const float4*)b)[tid];
  float o0 = (v.x - mu) * rs * wv.x + bv.x;
  float o1 = (v.y - mu) * rs * wv.y + bv.y;
  float o2 = (v.z - mu) * rs * wv.z + bv.z;
  float o3 = (v.w - mu) * rs * wv.w + bv.w;
  ushort4 u{f2b(o0), f2b(o1), f2b(o2), f2b(o3)};
  ((ushort4*)outb)[row * 256 + tid] = u;
  int pk = __builtin_amdgcn_cvt_pk_fp8_f32(o0, o1, 0, false);
  pk = __builtin_amdgcn_cvt_pk_fp8_f32(o2, o3, pk, true);
  outf8[row * 256 + tid] = pk;
}

__global__ __launch_bounds__(256) void ln2_fused_kernel(
    const unsigned short* __restrict__ y0, const unsigned short* __restrict__ y1,
    const unsigned short* __restrict__ x1b, const float* __restrict__ b2,
    const float* __restrict__ scalar_p, const float* __restrict__ w,
    const float* __restrict__ b, float* __restrict__ out) {
  const long row = blockIdx.x;
  const int tid = threadIdx.x;
  ushort4 a4 = ((const ushort4*)y0)[row * 256 + tid];
  ushort4 c4 = ((const ushort4*)y1)[row * 256 + tid];
  ushort4 xr = ((const ushort4*)x1b)[row * 256 + tid];
  float4 bias = ((const float4*)b2)[tid];
  const float scl = scalar_p[0];
  float4 v;
  v.x = b2f(xr.x) + scl * (b2f(a4.x) + b2f(c4.x) + bias.x);
  v.y = b2f(xr.y) + scl * (b2f(a4.y) + b2f(c4.y) + bias.y);
  v.z = b2f(xr.z) + scl * (b2f(a4.z) + b2f(c4.z) + bias.z);
  v.w = b2f(xr.w) + scl * (b2f(a4.w) + b2f(c4.w) + bias.w);
  float s = v.x + v.y + v.z + v.w;
  float ss = v.x * v.x + v.y * v.y + v.z * v.z + v.w * v.w;
#pragma unroll
  for (int off = 32; off > 0; off >>= 1) {
    s += __shfl_down(s, off);
    ss += __shfl_down(ss, off);
  }
  __shared__ float red[8];
  const int wid = tid >> 6, lane = tid & 63;
  if (lane == 0) { red[wid] = s; red[4 + wid] = ss; }
  __syncthreads();
  s = red[0] + red[1] + red[2] + red[3];
  ss = red[4] + red[5] + red[6] + red[7];
  const float mu = s * (1.0f / 1024.0f);
  const float var = ss * (1.0f / 1024.0f) - mu * mu;
  const float rs = rsqrtf(var + 1e-5f);
  float4 wv = ((const float4*)w)[tid];
  float4 bv = ((const float4*)b)[tid];
  float4 o;
  o.x = (v.x - mu) * rs * wv.x + bv.x;
  o.y = (v.y - mu) * rs * wv.y + bv.y;
  o.z = (v.z - mu) * rs * wv.z + bv.z;
  o.w = (v.w - mu) * rs * wv.w + bv.w;
  ((float4*)out)[row * 256 + tid] = o;
}

// ---------------- launch ----------------
extern "C" void kernel_launch(void* const* d_in, const int* in_sizes, int n_in,
                              void* d_out, int out_size, void* d_ws, size_t ws_size,
                              hipStream_t stream) {
  const float* x      = (const float*)d_in[0];
  const float* wconv  = (const float*)d_in[1];
  const float* scale  = (const float*)d_in[2];
  const float* ln1w   = (const float*)d_in[3];
  const float* ln1b   = (const float*)d_in[4];
  const float* W1     = (const float*)d_in[5];
  const float* b1     = (const float*)d_in[6];
  const float* W2     = (const float*)d_in[7];
  const float* b2     = (const float*)d_in[8];
  const float* scalar = (const float*)d_in[9];
  const float* ln2w   = (const float*)d_in[10];
  const float* ln2b   = (const float*)d_in[11];
  float* out = (float*)d_out;

  const unsigned SCL_1  = 0x7F7F7F7Fu;
  const unsigned SCL_64 = 0x79797979u;

  char* ws = (char*)d_ws;
  unsigned char* xT8   = (unsigned char*)ws;  ws += (size_t)4 * 1024 * 2048;
  unsigned char* T8    = (unsigned char*)ws;  ws += (size_t)2048 * 2048;
  unsigned char* W1f8  = (unsigned char*)ws;  ws += (size_t)4096 * 1024;
  unsigned char* W2f8  = (unsigned char*)ws;  ws += (size_t)4096 * 1024;
  float* y             = (float*)ws;          ws += (size_t)8192 * 1024 * 4;
  unsigned short* yb   = (unsigned short*)ws; ws += (size_t)2 * 8192 * 1024 * 2;
  unsigned short* x1b  = (unsigned short*)ws; ws += (size_t)8192 * 1024 * 2;
  unsigned char* x1f8  = (unsigned char*)ws;  ws += (size_t)8192 * 1024;
  unsigned char* h8    = (unsigned char*)ws;  ws += (size_t)8192 * 4096;

  cast_f8x64_kernel<<<4096, 256, 0, stream>>>(W1, (int*)W1f8);
  cast_f8x64_kernel<<<4096, 256, 0, stream>>>(W2, (int*)W2f8);
  build_T8_kernel<<<4096, 256, 0, stream>>>(wconv, (int*)T8);
  transpose_cast_f8_kernel<<<dim3(32, 64, 4), dim3(32, 8), 0, stream>>>(x, xT8);

  // GEMM1 (fp8, TRI, 128-tile): conv = T @ xT_b^T ; y = x + scale*conv
  gemm_f8<1, 1024, true><<<dim3(128, 1, 4), 256, 0, stream>>>(
      T8, xT8, 2048, 2048, 0L, (long)1024 * 2048, (long)2048 * 1024,
      8, 0, 0, SCL_64, SCL_1, x, scale, nullptr, y, nullptr, nullptr);
  // LN1
  ln_kernel<<<8192, 256, 0, stream>>>(y, ln1w, ln1b, x1b, (int*)x1f8);
  // GEMM2 (fp8, 256-tile 4-phase): h = gelu(x1 @ W1^T + b1) -> fp8
  gemm_f8_256<2, 4096><<<dim3(512, 1, 1), 512, 0, stream>>>(
      x1f8, W1f8, 1024, 1024, 0L, 0L, 0L,
      8, 8, 2, SCL_1, SCL_64, b1, nullptr, h8);
  // GEMM3 (fp8, 256-tile 4-phase) split-K=2: yb = bf16 partial h @ W2^T
  gemm_f8_256<0, 1024><<<dim3(128, 1, 2), 512, 0, stream>>>(
      h8, W2f8, 4096, 2048, 2048L, 2048L, (long)8192 * 1024,
      4, 4, 1, SCL_1, SCL_64, nullptr, yb, nullptr);
  // LN2
  ln2_fused_kernel<<<8192, 256, 0, stream>>>(
      yb, yb + (size_t)8192 * 1024, x1b, b2, scalar, ln2w, ln2b, out);
}

// Round 4
// 298.790 us; speedup vs baseline: 1.0076x; 1.0023x over previous
//
#include <hip/hip_runtime.h>
#include <cstdint>

typedef float floatx4 __attribute__((ext_vector_type(4)));
typedef float floatx16 __attribute__((ext_vector_type(16)));
typedef int intx8 __attribute__((ext_vector_type(8)));

__device__ __forceinline__ unsigned short f2b(float f) {
  union { float f; unsigned u; } v; v.f = f;
  return (unsigned short)((v.u + 0x7FFFu + ((v.u >> 16) & 1u)) >> 16);
}
__device__ __forceinline__ float b2f(unsigned short h) {
  union { unsigned u; float f; } v; v.u = ((unsigned)h) << 16;
  return v.f;
}

__device__ __forceinline__ void gload_lds16(const void* g, void* l) {
  __builtin_amdgcn_global_load_lds(
      (const __attribute__((address_space(1))) void*)g,
      (__attribute__((address_space(3))) void*)l, 16, 0, 0);
}

__device__ __forceinline__ intx8 lds_read32(const unsigned char* p) {
  union { intx8 v; int4 q[2]; } u;
  u.q[0] = *(const int4*)p;
  u.q[1] = *(const int4*)(p + 16);
  return u.v;
}

// Swizzled staging byte-column: LDS chunk (row, q) receives global chunk
// q ^ (row&3).  row-in-chunk = lane>>3, q = (lane>>1)&3, s = lane&1.
__device__ __forceinline__ int swz_scol(int lane) {
  const int q = (lane >> 1) & 3;
  const int r3 = (lane >> 3) & 3;
  const int sbit = lane & 1;
  return ((((q ^ r3) << 1) | sbit) << 4);
}

// ---------------- small prep kernels ----------------

__global__ void cast_f8x64_kernel(const float* __restrict__ in,
                                  int* __restrict__ out) {
  long i = (long)blockIdx.x * 256 + threadIdx.x;
  float4 v = ((const float4*)in)[i];
  int pk = __builtin_amdgcn_cvt_pk_fp8_f32(v.x * 64.0f, v.y * 64.0f, 0, false);
  pk = __builtin_amdgcn_cvt_pk_fp8_f32(v.z * 64.0f, v.w * 64.0f, pk, true);
  out[i] = pk;
}

__global__ void build_T8_kernel(const float* __restrict__ w,
                                int* __restrict__ T8) {
  long i = (long)blockIdx.x * 256 + threadIdx.x;
  int n = (int)(i >> 9);
  int m0 = (int)(i & 511) * 4;
  float v[4];
#pragma unroll
  for (int r = 0; r < 4; ++r) {
    int m = m0 + r;
    v[r] = (m <= n) ? w[n - m] * 64.0f : 0.0f;
  }
  int pk = __builtin_amdgcn_cvt_pk_fp8_f32(v[0], v[1], 0, false);
  pk = __builtin_amdgcn_cvt_pk_fp8_f32(v[2], v[3], pk, true);
  T8[i] = pk;
}

__global__ void transpose_cast_f8_kernel(const float* __restrict__ x,
                                         unsigned char* __restrict__ xT) {
  __shared__ float tile[32][33];
  int b = blockIdx.z;
  int n0 = blockIdx.y * 32;
  int d0 = blockIdx.x * 32;
  int tx = threadIdx.x;
  int ty = threadIdx.y;
  for (int i = ty; i < 32; i += 8)
    tile[i][tx] = x[((long)b * 2048 + n0 + i) * 1024 + d0 + tx];
  __syncthreads();
  float a = tile[ty * 4 + 0][tx];
  float c = tile[ty * 4 + 1][tx];
  float e = tile[ty * 4 + 2][tx];
  float f = tile[ty * 4 + 3][tx];
  int pk = __builtin_amdgcn_cvt_pk_fp8_f32(a, c, 0, false);
  pk = __builtin_amdgcn_cvt_pk_fp8_f32(e, f, pk, true);
  *(int*)(xT + ((long)b * 1024 + d0 + tx) * 2048 + n0 + ty * 4) = pk;
}

// ---------------- fp8 GEMM 128x128 (all GEMMs): C = A @ B^T ----------------
// r0-proven 2-phase sync-drain, 33 KB LDS -> 4 blocks/CU (16 waves/CU TLP).
// MFMA shape 32x32x64 (halves instruction count vs 16x16x128; same MX rate
// per ubench m59).  Per wave per K-tile: 8 MFMA, 16 ds_read_b128.
// XOR bank swizzle (measured conflict-free) on stage-source + frag reads.
// A/B frag: row = l&31, k-chunk = (l>>5)*32 within 64-wide k-slice.
// C/D frag (HW-verified, shape-determined): col = lane&31,
//   row = (reg&3) + 8*(reg>>2) + 4*(lane>>5), reg in [0,16).
// EPI 0: Cb = bf16(acc)                     (split-K partial)
// EPI 1: Cf = resid + scale[row]*acc        (conv epilogue)
// EPI 2: C8 = fp8(gelu_pade(acc+bias))      (MLP up)
template <int EPI, int NT, bool TRI>
__global__ __launch_bounds__(256, 4) void gemm_f8(
    const unsigned char* __restrict__ A, const unsigned char* __restrict__ B,
    int Kstride, int Kloop, long zsA, long zsB, long zsC,
    int rx, int ryb, int gxn, unsigned sclA, unsigned sclB,
    const float* __restrict__ resid, const float* __restrict__ scale,
    const float* __restrict__ bias,
    float* __restrict__ Cf, unsigned short* __restrict__ Cb,
    unsigned char* __restrict__ C8) {
  __shared__ __align__(16) unsigned char As[16 * 1040];
  __shared__ __align__(16) unsigned char Bs[16 * 1040];
  const int tid = threadIdx.x;
  const int wid = tid >> 6;
  const int lane = tid & 63;
  const int l32 = lane & 31;
  const int half = lane >> 5;
  const int wm = (wid >> 1) * 64;
  const int wn = (wid & 1) * 64;

  const int bid = blockIdx.x;
  const int xcd = bid & 7;
  const int ib = bid >> 3;
  const int ci = ib % rx;
  const int ri = ib / rx;
  long bm, bn;
  if (TRI) {
    bm = (long)(ri == 0 ? xcd : 15 - xcd) * 128;
    bn = (long)ci * 128;
  } else {
    const int gx = xcd % gxn;
    const int gy = xcd / gxn;
    bm = (long)(gy * ryb + ri) * 128;
    bn = (long)(gx * rx + ci) * 128;
  }
  const int bz = blockIdx.z;
  const unsigned char* Ab = A + zsA * bz;
  const unsigned char* Bb = B + zsB * bz;

  floatx16 acc[2][2];
#pragma unroll
  for (int i = 0; i < 2; ++i)
#pragma unroll
    for (int j = 0; j < 2; ++j)
#pragma unroll
      for (int e = 0; e < 16; ++e) acc[i][j][e] = 0.0f;

  const int srow = tid >> 3;
  const int scol = swz_scol(lane);   // pre-swizzled source column
  const unsigned char* gA[4];
  const unsigned char* gB[4];
  unsigned char* lA[4];
  unsigned char* lB[4];
#pragma unroll
  for (int p = 0; p < 4; ++p) {
    gA[p] = Ab + (bm + p * 32 + srow) * (long)Kstride + scol;
    gB[p] = Bb + (bn + p * 32 + srow) * (long)Kstride + scol;
    lA[p] = As + (p * 4 + wid) * 1040;
    lB[p] = Bs + (p * 4 + wid) * 1040;
  }

  // loop-invariant fragment byte offsets: frag (i, s): rows wm+i*32+l32,
  // 32B chunk c = s*2 + half, swizzled c^(row&3).
  int offA[2][2], offB[2][2];
#pragma unroll
  for (int i = 0; i < 2; ++i)
#pragma unroll
    for (int s = 0; s < 2; ++s) {
      const int ra = wm + i * 32 + l32;
      const int ca = (s * 2 + half) ^ (ra & 3);
      offA[i][s] = (ra >> 3) * 1040 + (ra & 7) * 128 + (ca << 5);
      const int rb = wn + i * 32 + l32;
      const int cb = (s * 2 + half) ^ (rb & 3);
      offB[i][s] = (rb >> 3) * 1040 + (rb & 7) * 128 + (cb << 5);
    }

  const int kend = TRI ? min(Kloop, (int)bm + 128) : Kloop;
  for (int kk = 0; kk < kend; kk += 128) {
    __syncthreads();
#pragma unroll
    for (int p = 0; p < 4; ++p) {
      gload_lds16(gA[p] + kk, lA[p]);
      gload_lds16(gB[p] + kk, lB[p]);
    }
    __syncthreads();
#pragma unroll
    for (int s = 0; s < 2; ++s) {
      intx8 b0 = lds_read32(Bs + offB[0][s]);
      intx8 b1 = lds_read32(Bs + offB[1][s]);
      intx8 a0 = lds_read32(As + offA[0][s]);
      intx8 a1 = lds_read32(As + offA[1][s]);
      acc[0][0] = __builtin_amdgcn_mfma_scale_f32_32x32x64_f8f6f4(
          a0, b0, acc[0][0], 0, 0, 0, sclA, 0, sclB);
      acc[0][1] = __builtin_amdgcn_mfma_scale_f32_32x32x64_f8f6f4(
          a0, b1, acc[0][1], 0, 0, 0, sclA, 0, sclB);
      acc[1][0] = __builtin_amdgcn_mfma_scale_f32_32x32x64_f8f6f4(
          a1, b0, acc[1][0], 0, 0, 0, sclA, 0, sclB);
      acc[1][1] = __builtin_amdgcn_mfma_scale_f32_32x32x64_f8f6f4(
          a1, b1, acc[1][1], 0, 0, 0, sclA, 0, sclB);
    }
  }

#pragma unroll
  for (int i = 0; i < 2; ++i)
#pragma unroll
    for (int j = 0; j < 2; ++j)
#pragma unroll
      for (int r = 0; r < 16; ++r) {
        long row = bm + wm + i * 32 + (r & 3) + 8 * (r >> 2) + 4 * half;
        long col = bn + wn + j * 32 + l32;
        long idx = (long)bz * zsC + row * (long)NT + col;
        float v = acc[i][j][r];
        if (EPI == 0) {
          Cb[idx] = f2b(v);
        } else if (EPI == 1) {
          Cf[idx] = resid[idx] + scale[row] * v;
        } else {
          v += bias[col];
          float u = v * (0.7978845608f + 0.0356774081f * v * v);
          float u2 = u * u;
          float t = __fdividef(u * (15.0f + u2), 15.0f + 6.0f * u2);
          t = fminf(fmaxf(t, -1.0f), 1.0f);
          float g = 0.5f * v * (1.0f + t);
          int pk = __builtin_amdgcn_cvt_pk_fp8_f32(g, 0.0f, 0, false);
          C8[idx] = (unsigned char)(pk & 0xFF);
        }
      }
}

// ---------------- LayerNorm over D=1024, one block per row ----------------
__global__ __launch_bounds__(256) void ln_kernel(
    const float* __restrict__ in, const float* __restrict__ w,
    const float* __restrict__ b, unsigned short* __restrict__ outb,
    int* __restrict__ outf8) {
  const long row = blockIdx.x;
  const int tid = threadIdx.x;
  float4 v = ((const float4*)in)[row * 256 + tid];
  float s = v.x + v.y + v.z + v.w;
  float ss = v.x * v.x + v.y * v.y + v.z * v.z + v.w * v.w;
#pragma unroll
  for (int off = 32; off > 0; off >>= 1) {
    s += __shfl_down(s, off);
    ss += __shfl_down(ss, off);
  }
  __shared__ float red[8];
  const int wid = tid >> 6, lane = tid & 63;
  if (lane == 0) { red[wid] = s; red[4 + wid] = ss; }
  __syncthreads();
  s = red[0] + red[1] + red[2] + red[3];
  ss = red[4] + red[5] + red[6] + red[7];
  const float mu = s * (1.0f / 1024.0f);
  const float var = ss * (1.0f / 1024.0f) - mu * mu;
  const float rs = rsqrtf(var + 1e-5f);
  float4 wv = ((const float4*)w)[tid];
  float4 bv = ((const float4*)b)[tid];
  float o0 = (v.x - mu) * rs * wv.x + bv.x;
  float o1 = (v.y - mu) * rs * wv.y + bv.y;
  float o2 = (v.z - mu) * rs * wv.z + bv.z;
  float o3 = (v.w - mu) * rs * wv.w + bv.w;
  ushort4 u{f2b(o0), f2b(o1), f2b(o2), f2b(o3)};
  ((ushort4*)outb)[row * 256 + tid] = u;
  int pk = __builtin_amdgcn_cvt_pk_fp8_f32(o0, o1, 0, false);
  pk = __builtin_amdgcn_cvt_pk_fp8_f32(o2, o3, pk, true);
  outf8[row * 256 + tid] = pk;
}

__global__ __launch_bounds__(256) void ln2_fused_kernel(
    const unsigned short* __restrict__ y0, const unsigned short* __restrict__ y1,
    const unsigned short* __restrict__ x1b, const float* __restrict__ b2,
    const float* __restrict__ scalar_p, const float* __restrict__ w,
    const float* __restrict__ b, float* __restrict__ out) {
  const long row = blockIdx.x;
  const int tid = threadIdx.x;
  ushort4 a4 = ((const ushort4*)y0)[row * 256 + tid];
  ushort4 c4 = ((const ushort4*)y1)[row * 256 + tid];
  ushort4 xr = ((const ushort4*)x1b)[row * 256 + tid];
  float4 bias = ((const float4*)b2)[tid];
  const float scl = scalar_p[0];
  float4 v;
  v.x = b2f(xr.x) + scl * (b2f(a4.x) + b2f(c4.x) + bias.x);
  v.y = b2f(xr.y) + scl * (b2f(a4.y) + b2f(c4.y) + bias.y);
  v.z = b2f(xr.z) + scl * (b2f(a4.z) + b2f(c4.z) + bias.z);
  v.w = b2f(xr.w) + scl * (b2f(a4.w) + b2f(c4.w) + bias.w);
  float s = v.x + v.y + v.z + v.w;
  float ss = v.x * v.x + v.y * v.y + v.z * v.z + v.w * v.w;
#pragma unroll
  for (int off = 32; off > 0; off >>= 1) {
    s += __shfl_down(s, off);
    ss += __shfl_down(ss, off);
  }
  __shared__ float red[8];
  const int wid = tid >> 6, lane = tid & 63;
  if (lane == 0) { red[wid] = s; red[4 + wid] = ss; }
  __syncthreads();
  s = red[0] + red[1] + red[2] + red[3];
  ss = red[4] + red[5] + red[6] + red[7];
  const float mu = s * (1.0f / 1024.0f);
  const float var = ss * (1.0f / 1024.0f) - mu * mu;
  const float rs = rsqrtf(var + 1e-5f);
  float4 wv = ((const float4*)w)[tid];
  float4 bv = ((const float4*)b)[tid];
  float4 o;
  o.x = (v.x - mu) * rs * wv.x + bv.x;
  o.y = (v.y - mu) * rs * wv.y + bv.y;
  o.z = (v.z - mu) * rs * wv.z + bv.z;
  o.w = (v.w - mu) * rs * wv.w + bv.w;
  ((float4*)out)[row * 256 + tid] = o;
}

// ---------------- launch ----------------
extern "C" void kernel_launch(void* const* d_in, const int* in_sizes, int n_in,
                              void* d_out, int out_size, void* d_ws, size_t ws_size,
                              hipStream_t stream) {
  const float* x      = (const float*)d_in[0];
  const float* wconv  = (const float*)d_in[1];
  const float* scale  = (const float*)d_in[2];
  const float* ln1w   = (const float*)d_in[3];
  const float* ln1b   = (const float*)d_in[4];
  const float* W1     = (const float*)d_in[5];
  const float* b1     = (const float*)d_in[6];
  const float* W2     = (const float*)d_in[7];
  const float* b2     = (const float*)d_in[8];
  const float* scalar = (const float*)d_in[9];
  const float* ln2w   = (const float*)d_in[10];
  const float* ln2b   = (const float*)d_in[11];
  float* out = (float*)d_out;

  const unsigned SCL_1  = 0x7F7F7F7Fu;  // 2^0 per-block scales
  const unsigned SCL_64 = 0x79797979u;  // 2^-6 (operand pre-scaled x64)

  char* ws = (char*)d_ws;
  unsigned char* xT8   = (unsigned char*)ws;  ws += (size_t)4 * 1024 * 2048;
  unsigned char* T8    = (unsigned char*)ws;  ws += (size_t)2048 * 2048;
  unsigned char* W1f8  = (unsigned char*)ws;  ws += (size_t)4096 * 1024;
  unsigned char* W2f8  = (unsigned char*)ws;  ws += (size_t)4096 * 1024;
  float* y             = (float*)ws;          ws += (size_t)8192 * 1024 * 4;
  unsigned short* yb   = (unsigned short*)ws; ws += (size_t)2 * 8192 * 1024 * 2;
  unsigned short* x1b  = (unsigned short*)ws; ws += (size_t)8192 * 1024 * 2;
  unsigned char* x1f8  = (unsigned char*)ws;  ws += (size_t)8192 * 1024;
  unsigned char* h8    = (unsigned char*)ws;  ws += (size_t)8192 * 4096;

  cast_f8x64_kernel<<<4096, 256, 0, stream>>>(W1, (int*)W1f8);
  cast_f8x64_kernel<<<4096, 256, 0, stream>>>(W2, (int*)W2f8);
  build_T8_kernel<<<4096, 256, 0, stream>>>(wconv, (int*)T8);
  transpose_cast_f8_kernel<<<dim3(32, 64, 4), dim3(32, 8), 0, stream>>>(x, xT8);

  // GEMM1 (fp8, TRI): conv = T @ xT_b^T ; y = x + scale*conv
  gemm_f8<1, 1024, true><<<dim3(128, 1, 4), 256, 0, stream>>>(
      T8, xT8, 2048, 2048, 0L, (long)1024 * 2048, (long)2048 * 1024,
      8, 0, 0, SCL_64, SCL_1, x, scale, nullptr, y, nullptr, nullptr);
  // LN1 -> x1 (bf16 residual + fp8 GEMM operand)
  ln_kernel<<<8192, 256, 0, stream>>>(y, ln1w, ln1b, x1b, (int*)x1f8);
  // GEMM2 (fp8): h = gelu(x1 @ W1^T + b1) -> fp8; rect 16x16, XCD grid 2 wide
  gemm_f8<2, 4096, false><<<dim3(2048, 1, 1), 256, 0, stream>>>(
      x1f8, W1f8, 1024, 1024, 0L, 0L, 0L,
      16, 16, 2, SCL_1, SCL_64, nullptr, nullptr, b1, nullptr, nullptr, h8);
  // GEMM3 (fp8) split-K=2: yb = bf16 partial h @ W2^T; rect 8x8 per XCD
  gemm_f8<0, 1024, false><<<dim3(512, 1, 2), 256, 0, stream>>>(
      h8, W2f8, 4096, 2048, 2048L, 2048L, (long)8192 * 1024,
      8, 8, 1, SCL_1, SCL_64, nullptr, nullptr, nullptr, nullptr, yb, nullptr);
  // LN2 fused: out = LN(x1 + scalar*(yb0+yb1+b2))
  ln2_fused_kernel<<<8192, 256, 0, stream>>>(
      yb, yb + (size_t)8192 * 1024, x1b, b2, scalar, ln2w, ln2b, out);
}

// Round 6
// 278.040 us; speedup vs baseline: 1.0828x; 1.0746x over previous
//
#include <hip/hip_runtime.h>
#include <cstdint>

typedef float floatx4 __attribute__((ext_vector_type(4)));
typedef float floatx16 __attribute__((ext_vector_type(16)));
typedef int intx8 __attribute__((ext_vector_type(8)));

__device__ __forceinline__ unsigned short f2b(float f) {
  union { float f; unsigned u; } v; v.f = f;
  return (unsigned short)((v.u + 0x7FFFu + ((v.u >> 16) & 1u)) >> 16);
}
__device__ __forceinline__ float b2f(unsigned short h) {
  union { unsigned u; float f; } v; v.u = ((unsigned)h) << 16;
  return v.f;
}

__device__ __forceinline__ void gload_lds16(const void* g, void* l) {
  __builtin_amdgcn_global_load_lds(
      (const __attribute__((address_space(1))) void*)g,
      (__attribute__((address_space(3))) void*)l, 16, 0, 0);
}

// Read 32B fragment from 16B-XOR-swizzled LDS via two explicit 16B offsets.
// (r5 bug: hi = lo^16 is wrong when the chunk base (k*1040, 1040=1024+16)
// carries into bit 4 of the summed address; offsets must be precomputed.)
__device__ __forceinline__ intx8 lds_read32s(const unsigned char* base,
                                             int lo, int hi) {
  union { intx8 v; int4 q[2]; } u;
  u.q[0] = *(const int4*)(base + lo);
  u.q[1] = *(const int4*)(base + hi);
  return u.v;
}

// Staging source byte-column: LDS seg-position p (=lane&7) of row r receives
// global seg p^(r&7); row-in-chunk = lane>>3.
__device__ __forceinline__ int swz_scol(int lane) {
  return (((lane & 7) ^ ((lane >> 3) & 7)) << 4);
}

// ---------------- fused prep kernel (4 ops, 1 launch) ----------------
// blocks [0,4096):      W1 f32 -> fp8(x64)
// blocks [4096,8192):   W2 f32 -> fp8(x64)
// blocks [8192,12288):  T8[n][m] = fp8(64*w[n-m]), m<=n else 0
// blocks [12288,20480): x (B,2048,1024) f32 -> xT8 (B,1024,2048) fp8
__global__ __launch_bounds__(256) void prep_kernel(
    const float* __restrict__ W1, const float* __restrict__ W2,
    const float* __restrict__ wconv, const float* __restrict__ x,
    int* __restrict__ W1f8, int* __restrict__ W2f8,
    int* __restrict__ T8, unsigned char* __restrict__ xT) {
  const int bid = blockIdx.x;
  const int tid = threadIdx.x;
  if (bid < 8192) {
    const float* in = (bid < 4096) ? W1 : W2;
    int* out = (bid < 4096) ? W1f8 : W2f8;
    long i = (long)(bid & 4095) * 256 + tid;
    float4 v = ((const float4*)in)[i];
    int pk = __builtin_amdgcn_cvt_pk_fp8_f32(v.x * 64.0f, v.y * 64.0f, 0, false);
    pk = __builtin_amdgcn_cvt_pk_fp8_f32(v.z * 64.0f, v.w * 64.0f, pk, true);
    out[i] = pk;
  } else if (bid < 12288) {
    long i = (long)(bid - 8192) * 256 + tid;
    int n = (int)(i >> 9);
    int m0 = (int)(i & 511) * 4;
    float v[4];
#pragma unroll
    for (int r = 0; r < 4; ++r) {
      int m = m0 + r;
      v[r] = (m <= n) ? wconv[n - m] * 64.0f : 0.0f;
    }
    int pk = __builtin_amdgcn_cvt_pk_fp8_f32(v[0], v[1], 0, false);
    pk = __builtin_amdgcn_cvt_pk_fp8_f32(v[2], v[3], pk, true);
    T8[i] = pk;
  } else {
    __shared__ float tile[32][33];
    const int t = bid - 12288;
    const int d0 = (t & 31) * 32;
    const int n0 = ((t >> 5) & 63) * 32;
    const int b = t >> 11;
    const int tx = tid & 31;
    const int ty = tid >> 5;  // 0..7
    for (int i = ty; i < 32; i += 8)
      tile[i][tx] = x[((long)b * 2048 + n0 + i) * 1024 + d0 + tx];
    __syncthreads();
    float a = tile[ty * 4 + 0][tx];
    float c = tile[ty * 4 + 1][tx];
    float e = tile[ty * 4 + 2][tx];
    float f = tile[ty * 4 + 3][tx];
    int pk = __builtin_amdgcn_cvt_pk_fp8_f32(a, c, 0, false);
    pk = __builtin_amdgcn_cvt_pk_fp8_f32(e, f, pk, true);
    *(int*)(xT + ((long)b * 1024 + d0 + tx) * 2048 + n0 + ty * 4) = pk;
  }
}

// ---------------- fp8 GEMM 128x128: C = A @ B^T ----------------
// 2-phase sync-drain, 33 KB LDS -> 4 blocks/CU (16 waves/CU TLP).
// MFMA 32x32x64; 16B-granular XOR bank swizzle (seg q of row r stored at
// position q^(r&7)): per 8-row group lanes cover all 32 banks exactly once.
// TRI (GEMM1): triangular K + split-K=2 folded into grid.x; EPI=0 writes
// bf16 partials at Cb + sp*zsP (summed in LN1).
// EPI 0: Cb = bf16(acc)                (split-K partial)
// EPI 2: C8 = fp8(gelu_pade(acc+bias)) (MLP up)
template <int EPI, int NT, bool TRI>
__global__ __launch_bounds__(256, 4) void gemm_f8(
    const unsigned char* __restrict__ A, const unsigned char* __restrict__ B,
    int Kstride, int Kloop, long zsA, long zsB, long zsC, long zsP,
    int rx, int ryb, int gxn, unsigned sclA, unsigned sclB,
    const float* __restrict__ bias,
    unsigned short* __restrict__ Cb, unsigned char* __restrict__ C8) {
  __shared__ __align__(16) unsigned char As[16 * 1040];
  __shared__ __align__(16) unsigned char Bs[16 * 1040];
  const int tid = threadIdx.x;
  const int wid = tid >> 6;
  const int lane = tid & 63;
  const int l32 = lane & 31;
  const int half = lane >> 5;
  const int wm = (wid >> 1) * 64;
  const int wn = (wid & 1) * 64;

  const int bid = blockIdx.x;
  const int xcd = bid & 7;
  const int ib = bid >> 3;
  long bm, bn;
  int kstart, kend;
  long pofs = 0;
  if (TRI) {
    // ib in [0,32): ci = d-tile (8), ri = row-set (2), sp = K-split (2)
    const int ci = ib & 7;
    const int ri = (ib >> 3) & 1;
    const int sp = ib >> 4;
    bm = (long)(ri == 0 ? xcd : 15 - xcd) * 128;
    bn = (long)ci * 128;
    const int T = (int)(bm >> 7) + 1;      // K-tiles for this row
    const int h = (T + 1) >> 1;            // split point (sp0 gets ceil)
    kstart = (sp ? h : 0) * 128;
    kend = (sp ? T : h) * 128;
    pofs = (long)sp * zsP;
  } else {
    const int ci = ib % rx;
    const int ri = ib / rx;
    const int gx = xcd % gxn;
    const int gy = xcd / gxn;
    bm = (long)(gy * ryb + ri) * 128;
    bn = (long)(gx * rx + ci) * 128;
    kstart = 0;
    kend = Kloop;
  }
  const int bz = blockIdx.z;
  const unsigned char* Ab = A + zsA * bz;
  const unsigned char* Bb = B + zsB * bz;

  floatx16 acc[2][2];
#pragma unroll
  for (int i = 0; i < 2; ++i)
#pragma unroll
    for (int j = 0; j < 2; ++j)
#pragma unroll
      for (int e = 0; e < 16; ++e) acc[i][j][e] = 0.0f;

  const int srow = tid >> 3;
  const int scol = swz_scol(lane);   // pre-swizzled source column (16B gran)
  const unsigned char* gA[4];
  const unsigned char* gB[4];
  unsigned char* lA[4];
  unsigned char* lB[4];
#pragma unroll
  for (int p = 0; p < 4; ++p) {
    gA[p] = Ab + (bm + p * 32 + srow) * (long)Kstride + scol;
    gB[p] = Bb + (bn + p * 32 + srow) * (long)Kstride + scol;
    lA[p] = As + (p * 4 + wid) * 1040;  // wave-uniform base (+lane*16 implicit)
    lB[p] = Bs + (p * 4 + wid) * 1040;
  }

  // frag (i,s): rows wm+i*32+l32, global 16B segs q0 = s*4+half*2 and q0+1;
  // stored at position q^(row&7).  Precompute BOTH offsets (no ^16 on sums).
  int offA_lo[2][2], offA_hi[2][2], offB_lo[2][2], offB_hi[2][2];
#pragma unroll
  for (int i = 0; i < 2; ++i)
#pragma unroll
    for (int s = 0; s < 2; ++s) {
      const int q0 = s * 4 + half * 2;
      const int ra = (int)wm + i * 32 + l32;
      const int baseA = (ra >> 3) * 1040 + (ra & 7) * 128;
      offA_lo[i][s] = baseA + ((q0 ^ (ra & 7)) << 4);
      offA_hi[i][s] = baseA + (((q0 + 1) ^ (ra & 7)) << 4);
      const int rb = (int)wn + i * 32 + l32;
      const int baseB = (rb >> 3) * 1040 + (rb & 7) * 128;
      offB_lo[i][s] = baseB + ((q0 ^ (rb & 7)) << 4);
      offB_hi[i][s] = baseB + (((q0 + 1) ^ (rb & 7)) << 4);
    }

  for (int kk = kstart; kk < kend; kk += 128) {
    __syncthreads();
#pragma unroll
    for (int p = 0; p < 4; ++p) {
      gload_lds16(gA[p] + kk, lA[p]);
      gload_lds16(gB[p] + kk, lB[p]);
    }
    __syncthreads();
#pragma unroll
    for (int s = 0; s < 2; ++s) {
      intx8 b0 = lds_read32s(Bs, offB_lo[0][s], offB_hi[0][s]);
      intx8 b1 = lds_read32s(Bs, offB_lo[1][s], offB_hi[1][s]);
      intx8 a0 = lds_read32s(As, offA_lo[0][s], offA_hi[0][s]);
      intx8 a1 = lds_read32s(As, offA_lo[1][s], offA_hi[1][s]);
      acc[0][0] = __builtin_amdgcn_mfma_scale_f32_32x32x64_f8f6f4(
          a0, b0, acc[0][0], 0, 0, 0, sclA, 0, sclB);
      acc[0][1] = __builtin_amdgcn_mfma_scale_f32_32x32x64_f8f6f4(
          a0, b1, acc[0][1], 0, 0, 0, sclA, 0, sclB);
      acc[1][0] = __builtin_amdgcn_mfma_scale_f32_32x32x64_f8f6f4(
          a1, b0, acc[1][0], 0, 0, 0, sclA, 0, sclB);
      acc[1][1] = __builtin_amdgcn_mfma_scale_f32_32x32x64_f8f6f4(
          a1, b1, acc[1][1], 0, 0, 0, sclA, 0, sclB);
    }
  }

  // C/D frag (HW-verified): col = lane&31, row = (r&3)+8*(r>>2)+4*half
#pragma unroll
  for (int i = 0; i < 2; ++i)
#pragma unroll
    for (int j = 0; j < 2; ++j)
#pragma unroll
      for (int r = 0; r < 16; ++r) {
        long row = bm + wm + i * 32 + (r & 3) + 8 * (r >> 2) + 4 * half;
        long col = bn + wn + j * 32 + l32;
        long idx = pofs + (long)bz * zsC + row * (long)NT + col;
        float v = acc[i][j][r];
        if (EPI == 0) {
          Cb[idx] = f2b(v);
        } else {
          v += bias[col];
          float u = v * (0.7978845608f + 0.0356774081f * v * v);
          float u2 = u * u;
          float t = __fdividef(u * (15.0f + u2), 15.0f + 6.0f * u2);
          t = fminf(fmaxf(t, -1.0f), 1.0f);
          float g = 0.5f * v * (1.0f + t);
          int pk = __builtin_amdgcn_cvt_pk_fp8_f32(g, 0.0f, 0, false);
          C8[idx] = (unsigned char)(pk & 0xFF);
        }
      }
}

// ---------------- LN1 fused: v = x + scale[n]*(c0+c1); LN -> bf16 + fp8 ----
__global__ __launch_bounds__(256) void ln1_kernel(
    const float* __restrict__ x, const unsigned short* __restrict__ c0,
    const unsigned short* __restrict__ c1, const float* __restrict__ scale,
    const float* __restrict__ w, const float* __restrict__ b,
    unsigned short* __restrict__ outb, int* __restrict__ outf8) {
  const long row = blockIdx.x;
  const int tid = threadIdx.x;
  float4 xv = ((const float4*)x)[row * 256 + tid];
  ushort4 a4 = ((const ushort4*)c0)[row * 256 + tid];
  ushort4 e4 = ((const ushort4*)c1)[row * 256 + tid];
  const float sc = scale[row & 2047];
  float4 v;
  v.x = xv.x + sc * (b2f(a4.x) + b2f(e4.x));
  v.y = xv.y + sc * (b2f(a4.y) + b2f(e4.y));
  v.z = xv.z + sc * (b2f(a4.z) + b2f(e4.z));
  v.w = xv.w + sc * (b2f(a4.w) + b2f(e4.w));
  float s = v.x + v.y + v.z + v.w;
  float ss = v.x * v.x + v.y * v.y + v.z * v.z + v.w * v.w;
#pragma unroll
  for (int off = 32; off > 0; off >>= 1) {
    s += __shfl_down(s, off);
    ss += __shfl_down(ss, off);
  }
  __shared__ float red[8];
  const int wid = tid >> 6, lane = tid & 63;
  if (lane == 0) { red[wid] = s; red[4 + wid] = ss; }
  __syncthreads();
  s = red[0] + red[1] + red[2] + red[3];
  ss = red[4] + red[5] + red[6] + red[7];
  const float mu = s * (1.0f / 1024.0f);
  const float var = ss * (1.0f / 1024.0f) - mu * mu;
  const float rs = rsqrtf(var + 1e-5f);
  float4 wv = ((const float4*)w)[tid];
  float4 bv = ((const float4*)b)[tid];
  float o0 = (v.x - mu) * rs * wv.x + bv.x;
  float o1 = (v.y - mu) * rs * wv.y + bv.y;
  float o2 = (v.z - mu) * rs * wv.z + bv.z;
  float o3 = (v.w - mu) * rs * wv.w + bv.w;
  ushort4 u{f2b(o0), f2b(o1), f2b(o2), f2b(o3)};
  ((ushort4*)outb)[row * 256 + tid] = u;
  int pk = __builtin_amdgcn_cvt_pk_fp8_f32(o0, o1, 0, false);
  pk = __builtin_amdgcn_cvt_pk_fp8_f32(o2, o3, pk, true);
  outf8[row * 256 + tid] = pk;
}

// LN2 fused: v = x1 + scalar*(y0+y1+b2); out = LN(v)*w + b
__global__ __launch_bounds__(256) void ln2_fused_kernel(
    const unsigned short* __restrict__ y0, const unsigned short* __restrict__ y1,
    const unsigned short* __restrict__ x1b, const float* __restrict__ b2,
    const float* __restrict__ scalar_p, const float* __restrict__ w,
    const float* __restrict__ b, float* __restrict__ out) {
  const long row = blockIdx.x;
  const int tid = threadIdx.x;
  ushort4 a4 = ((const ushort4*)y0)[row * 256 + tid];
  ushort4 c4 = ((const ushort4*)y1)[row * 256 + tid];
  ushort4 xr = ((const ushort4*)x1b)[row * 256 + tid];
  float4 bias = ((const float4*)b2)[tid];
  const float scl = scalar_p[0];
  float4 v;
  v.x = b2f(xr.x) + scl * (b2f(a4.x) + b2f(c4.x) + bias.x);
  v.y = b2f(xr.y) + scl * (b2f(a4.y) + b2f(c4.y) + bias.y);
  v.z = b2f(xr.z) + scl * (b2f(a4.z) + b2f(c4.z) + bias.z);
  v.w = b2f(xr.w) + scl * (b2f(a4.w) + b2f(c4.w) + bias.w);
  float s = v.x + v.y + v.z + v.w;
  float ss = v.x * v.x + v.y * v.y + v.z * v.z + v.w * v.w;
#pragma unroll
  for (int off = 32; off > 0; off >>= 1) {
    s += __shfl_down(s, off);
    ss += __shfl_down(ss, off);
  }
  __shared__ float red[8];
  const int wid = tid >> 6, lane = tid & 63;
  if (lane == 0) { red[wid] = s; red[4 + wid] = ss; }
  __syncthreads();
  s = red[0] + red[1] + red[2] + red[3];
  ss = red[4] + red[5] + red[6] + red[7];
  const float mu = s * (1.0f / 1024.0f);
  const float var = ss * (1.0f / 1024.0f) - mu * mu;
  const float rs = rsqrtf(var + 1e-5f);
  float4 wv = ((const float4*)w)[tid];
  float4 bv = ((const float4*)b)[tid];
  float4 o;
  o.x = (v.x - mu) * rs * wv.x + bv.x;
  o.y = (v.y - mu) * rs * wv.y + bv.y;
  o.z = (v.z - mu) * rs * wv.z + bv.z;
  o.w = (v.w - mu) * rs * wv.w + bv.w;
  ((float4*)out)[row * 256 + tid] = o;
}

// ---------------- launch ----------------
extern "C" void kernel_launch(void* const* d_in, const int* in_sizes, int n_in,
                              void* d_out, int out_size, void* d_ws, size_t ws_size,
                              hipStream_t stream) {
  const float* x      = (const float*)d_in[0];
  const float* wconv  = (const float*)d_in[1];
  const float* scale  = (const float*)d_in[2];
  const float* ln1w   = (const float*)d_in[3];
  const float* ln1b   = (const float*)d_in[4];
  const float* W1     = (const float*)d_in[5];
  const float* b1     = (const float*)d_in[6];
  const float* W2     = (const float*)d_in[7];
  const float* b2     = (const float*)d_in[8];
  const float* scalar = (const float*)d_in[9];
  const float* ln2w   = (const float*)d_in[10];
  const float* ln2b   = (const float*)d_in[11];
  float* out = (float*)d_out;

  const unsigned SCL_1  = 0x7F7F7F7Fu;  // 2^0 per-block scales
  const unsigned SCL_64 = 0x79797979u;  // 2^-6 (operand pre-scaled x64)

  char* ws = (char*)d_ws;
  unsigned char* xT8   = (unsigned char*)ws;  ws += (size_t)4 * 1024 * 2048;
  unsigned char* T8    = (unsigned char*)ws;  ws += (size_t)2048 * 2048;
  unsigned char* W1f8  = (unsigned char*)ws;  ws += (size_t)4096 * 1024;
  unsigned char* W2f8  = (unsigned char*)ws;  ws += (size_t)4096 * 1024;
  float* y             = (float*)ws;          ws += (size_t)8192 * 1024 * 4;  // unused (kept)
  unsigned short* yb   = (unsigned short*)ws; ws += (size_t)2 * 8192 * 1024 * 2;
  unsigned short* x1b  = (unsigned short*)ws; ws += (size_t)8192 * 1024 * 2;
  unsigned char* x1f8  = (unsigned char*)ws;  ws += (size_t)8192 * 1024;
  unsigned char* h8    = (unsigned char*)ws;  ws += (size_t)8192 * 4096;
  (void)y;

  // prep: all 4 casts/builds in one launch
  prep_kernel<<<20480, 256, 0, stream>>>(W1, W2, wconv, x,
                                         (int*)W1f8, (int*)W2f8, (int*)T8, xT8);

  // GEMM1 (fp8, TRI, split-K=2): conv partials (bf16) = T @ xT_b^T -> yb0/yb1
  // grid.x = 256 (8 d-tiles x 2 row-sets x 2 splits, XCD-swizzled), z = batch
  gemm_f8<0, 1024, true><<<dim3(256, 1, 4), 256, 0, stream>>>(
      T8, xT8, 2048, 2048, 0L, (long)1024 * 2048, (long)2048 * 1024,
      (long)8192 * 1024, 8, 0, 0, SCL_64, SCL_1, nullptr, yb, nullptr);
  // LN1 fused: x1 = LN(x + scale*(c0+c1)) -> bf16 residual + fp8 operand
  ln1_kernel<<<8192, 256, 0, stream>>>(
      x, yb, yb + (size_t)8192 * 1024, scale, ln1w, ln1b, x1b, (int*)x1f8);
  // GEMM2 (fp8): h = gelu(x1 @ W1^T + b1) -> fp8; rect 16x16, XCD grid 2 wide
  gemm_f8<2, 4096, false><<<dim3(2048, 1, 1), 256, 0, stream>>>(
      x1f8, W1f8, 1024, 1024, 0L, 0L, 0L, 0L,
      16, 16, 2, SCL_1, SCL_64, b1, nullptr, h8);
  // GEMM3 (fp8) split-K=2: yb = bf16 partial h @ W2^T; rect 8x8 per XCD
  gemm_f8<0, 1024, false><<<dim3(512, 1, 2), 256, 0, stream>>>(
      h8, W2f8, 4096, 2048, 2048L, 2048L, (long)8192 * 1024, 0L,
      8, 8, 1, SCL_1, SCL_64, nullptr, yb, nullptr);
  // LN2 fused: out = LN(x1 + scalar*(yb0+yb1+b2))
  ln2_fused_kernel<<<8192, 256, 0, stream>>>(
      yb, yb + (size_t)8192 * 1024, x1b, b2, scalar, ln2w, ln2b, out);
}